// Round 3
// baseline (503.917 us; speedup 1.0000x reference)
//
#include <hip/hip_runtime.h>
#include <math.h>

#define THREADS 256
#define NPAIR (8*256*256)

// 16-wide float vector: a single SSA value to the compiler -> cannot be
// demoted to scratch the way float[64] allocas were (R1/R2: VGPR=76 +
// scratch spills -> 427us). 4 of these = one 64-float activation vector.
typedef float v16 __attribute__((ext_vector_type(16)));

// Packed weights built by prep_kernel.
// g_W1T[k][0..8] = W1[:,k], g_W1T[k][9] = b1[k], rest 0.  (64 rows x 16 floats)
__device__ float g_W1T[64 * 16];
// g_Wg1T[u][j] = Wg1[j][u]   (64 rows x 128 floats)
__device__ float g_Wg1T[64 * 128];
// g_gw[k] = ln_gamma[k] * Wo[k]
__device__ float g_gw[64];
// g_cc[0] = sum_k ln_beta[k]*Wo[k], g_cc[1] = sum_k ln_gamma[k]*Wo[k]
__device__ float g_cc[2];

__global__ void prep_kernel(const float* __restrict__ W1, const float* __restrict__ b1,
                            const float* __restrict__ Wg1,
                            const float* __restrict__ ln_g, const float* __restrict__ ln_b,
                            const float* __restrict__ Wo)
{
    int t = threadIdx.x;
    for (int i = t; i < 64 * 16; i += THREADS) {
        int k = i >> 4, j = i & 15;
        float v = 0.f;
        if (j < 9)       v = W1[j * 64 + k];
        else if (j == 9) v = b1[k];
        g_W1T[i] = v;
    }
    for (int i = t; i < 64 * 128; i += THREADS) {
        int u = i >> 7, j = i & 127;
        g_Wg1T[i] = Wg1[j * 64 + u];
    }
    if (t < 64) g_gw[t] = ln_g[t] * Wo[t];
    if (t == 0) {
        float c0 = 0.f, c1 = 0.f;
        for (int k = 0; k < 64; ++k) { c0 += ln_b[k] * Wo[k]; c1 += ln_g[k] * Wo[k]; }
        g_cc[0] = c0; g_cc[1] = c1;
    }
}

// 9 fourier features as named scalar members (no array -> no alloca risk).
struct Feat { float f0, f1, f2, f3, f4, f5, f6, f7, f8; };

__device__ __forceinline__ Feat build_feat(float x, float s)
{
    Feat r;
    r.f0 = x * s;
    r.f1 = __sinf(x)        * s;  r.f2 = __cosf(x)        * s;
    r.f3 = __sinf(2.f * x)  * s;  r.f4 = __cosf(2.f * x)  * s;
    r.f5 = __sinf(4.f * x)  * s;  r.f6 = __cosf(4.f * x)  * s;
    r.f7 = __sinf(8.f * x)  * s;  r.f8 = __cosf(8.f * x)  * s;
    return r;
}

__device__ __forceinline__ float silu(float h)
{
    return h * __builtin_amdgcn_rcpf(1.f + __expf(-h));
}

// e = film(silu(x@W1+b1) @ W2 + b2); L1 fused into the k-loop.
__device__ __forceinline__ void encode_channel(const Feat& x,
                                               const float* __restrict__ W2,
                                               const float* __restrict__ b2,
                                               const float* __restrict__ fg,
                                               const float* __restrict__ fb,
                                               v16& a0, v16& a1, v16& a2, v16& a3)
{
    const v16* b2v = (const v16*)b2;
    a0 = b2v[0]; a1 = b2v[1]; a2 = b2v[2]; a3 = b2v[3];
#pragma unroll 2
    for (int k = 0; k < 64; ++k) {
        const float* w1r = &g_W1T[k * 16];     // wave-uniform -> scalar loads
        float h = w1r[9];
        h = fmaf(x.f0, w1r[0], h); h = fmaf(x.f1, w1r[1], h); h = fmaf(x.f2, w1r[2], h);
        h = fmaf(x.f3, w1r[3], h); h = fmaf(x.f4, w1r[4], h); h = fmaf(x.f5, w1r[5], h);
        h = fmaf(x.f6, w1r[6], h); h = fmaf(x.f7, w1r[7], h); h = fmaf(x.f8, w1r[8], h);
        h = silu(h);
        const v16* w2v = (const v16*)(W2 + (k << 6));  // wave-uniform row
        a0 += w2v[0] * h; a1 += w2v[1] * h; a2 += w2v[2] * h; a3 += w2v[3] * h;
    }
    const v16* fgv = (const v16*)fg;
    const v16* fbv = (const v16*)fb;
    a0 = a0 * fgv[0] + fbv[0]; a1 = a1 * fgv[1] + fbv[1];
    a2 = a2 * fgv[2] + fbv[2]; a3 = a3 * fgv[3] + fbv[3];
}

__device__ __forceinline__ float hsum(v16 v)
{
    float s01 = (v[0] + v[8])  + (v[4] + v[12]);
    float s23 = (v[1] + v[9])  + (v[5] + v[13]);
    float s45 = (v[2] + v[10]) + (v[6] + v[14]);
    float s67 = (v[3] + v[11]) + (v[7] + v[15]);
    return (s01 + s23) + (s45 + s67);
}

__global__ __launch_bounds__(THREADS, 2) void fused_kernel(
    const float* __restrict__ coords, const float* __restrict__ cost,
    const float* __restrict__ lscale,
    const float* __restrict__ W2, const float* __restrict__ b2,
    const float* __restrict__ fgam, const float* __restrict__ fbet,
    const float* __restrict__ bg1, const float* __restrict__ Wg2,
    const float* __restrict__ bg2, const float* __restrict__ gtemp,
    const float* __restrict__ bo,
    float* __restrict__ out)
{
    int p = blockIdx.x * THREADS + threadIdx.x;
    int b = p >> 16;
    int ij = p & 0xFFFF;
    int i = ij >> 8, j = ij & 255;

    float c = cost[p];
    const float* cb = coords + (b << 9);
    float xi = cb[2 * i], yi = cb[2 * i + 1];
    float xj = cb[2 * j], yj = cb[2 * j + 1];
    float ang = atan2f(yi - yj, xi - xj);

    float s0 = __expf(lscale[0]);
    float s1 = __expf(lscale[1]);

    v16 e0q0, e0q1, e0q2, e0q3;
    v16 e1q0, e1q1, e1q2, e1q3;

    {
        Feat xc = build_feat(c, s0);
        encode_channel(xc, W2, b2, fgam,      fbet,      e0q0, e0q1, e0q2, e0q3);
    }
    {
        Feat xa = build_feat(ang, s1);
        encode_channel(xa, W2, b2, fgam + 64, fbet + 64, e1q0, e1q1, e1q2, e1q3);
    }

    // Gate: logits = silu([e0|e1] @ Wg1 + bg1) @ Wg2 + bg2.
    // 4 partial accumulators: dep chain 32 deep instead of 128.
    float l0 = bg2[0], l1 = bg2[1];
#pragma unroll 2
    for (int u = 0; u < 64; ++u) {
        const float* wr = &g_Wg1T[u * 128];    // wave-uniform -> scalar loads
        float g0 = bg1[u], g1 = 0.f, g2 = 0.f, g3 = 0.f;
#pragma unroll
        for (int k = 0; k < 16; ++k) {
            g0 = fmaf(e0q0[k], wr[k],      g0);
            g1 = fmaf(e0q1[k], wr[16 + k], g1);
            g2 = fmaf(e0q2[k], wr[32 + k], g2);
            g3 = fmaf(e0q3[k], wr[48 + k], g3);
        }
#pragma unroll
        for (int k = 0; k < 16; ++k) {
            g0 = fmaf(e1q0[k], wr[64 + k],  g0);
            g1 = fmaf(e1q1[k], wr[80 + k],  g1);
            g2 = fmaf(e1q2[k], wr[96 + k],  g2);
            g3 = fmaf(e1q3[k], wr[112 + k], g3);
        }
        float g = silu((g0 + g1) + (g2 + g3));
        l0 = fmaf(g, Wg2[2 * u],     l0);
        l1 = fmaf(g, Wg2[2 * u + 1], l1);
    }

    // softmax over 2 with temperature exp(gtemp): w1 = sigmoid((l1-l0)/T)
    float invT = __builtin_amdgcn_rcpf(__expf(gtemp[0]));
    float d = (l1 - l0) * invT;
    float w1 = __builtin_amdgcn_rcpf(1.f + __expf(-d));
    float w0 = 1.f - w1;

    // fused = w0*e0 + w1*e1; LayerNorm folded into the output head:
    // out = rs*(dot(f,gw) - mu*C1) + C0 + bo
    v16 f0 = e0q0 * w0 + e1q0 * w1;
    v16 f1 = e0q1 * w0 + e1q1 * w1;
    v16 f2 = e0q2 * w0 + e1q2 * w1;
    v16 f3 = e0q3 * w0 + e1q3 * w1;

    float mu = hsum((f0 + f1) + (f2 + f3)) * (1.f / 64.f);
    v16 d0 = f0 - mu, d1 = f1 - mu, d2 = f2 - mu, d3 = f3 - mu;
    float var = hsum((d0 * d0 + d1 * d1) + (d2 * d2 + d3 * d3)) * (1.f / 64.f);
    float rs = __builtin_amdgcn_rsqf(var + 1e-5f);

    const v16* gwv = (const v16*)g_gw;
    float dot = hsum((f0 * gwv[0] + f1 * gwv[1]) + (f2 * gwv[2] + f3 * gwv[3]));
    out[p] = fmaf(rs, dot - mu * g_cc[1], g_cc[0] + bo[0]);
}

extern "C" void kernel_launch(void* const* d_in, const int* in_sizes, int n_in,
                              void* d_out, int out_size, void* d_ws, size_t ws_size,
                              hipStream_t stream)
{
    const float* coords = (const float*)d_in[0];
    const float* cost   = (const float*)d_in[1];
    const float* lscale = (const float*)d_in[2];
    const float* W1     = (const float*)d_in[3];
    const float* b1     = (const float*)d_in[4];
    const float* W2     = (const float*)d_in[5];
    const float* b2     = (const float*)d_in[6];
    const float* fg     = (const float*)d_in[7];
    const float* fb     = (const float*)d_in[8];
    const float* Wg1    = (const float*)d_in[9];
    const float* bg1    = (const float*)d_in[10];
    const float* Wg2    = (const float*)d_in[11];
    const float* bg2    = (const float*)d_in[12];
    const float* gt     = (const float*)d_in[13];
    const float* lng    = (const float*)d_in[14];
    const float* lnb    = (const float*)d_in[15];
    const float* Wo     = (const float*)d_in[16];
    const float* bo     = (const float*)d_in[17];
    float* out = (float*)d_out;

    prep_kernel<<<1, THREADS, 0, stream>>>(W1, b1, Wg1, lng, lnb, Wo);
    fused_kernel<<<NPAIR / THREADS, THREADS, 0, stream>>>(
        coords, cost, lscale, W2, b2, fg, fb, bg1, Wg2, bg2, gt, bo, out);
}

// Round 4
// 180.544 us; speedup vs baseline: 2.7911x; 2.7911x over previous
//
#include <hip/hip_runtime.h>
#include <math.h>

typedef _Float16 h8 __attribute__((ext_vector_type(8)));
typedef _Float16 h2 __attribute__((ext_vector_type(2)));
typedef float    f4 __attribute__((ext_vector_type(4)));
typedef float    f2 __attribute__((ext_vector_type(2)));

#define NPAIR (8*256*256)
#define NTILE (NPAIR/16)          // 32768 tiles of 16 rows
#define BLOCKS 2048
#define ITERS (NTILE/(BLOCKS*4))  // 4 tiles per wave

#define MFMA(a,b,c) __builtin_amdgcn_mfma_f32_16x16x32_f16((a),(b),(c),0,0,0)

// Fragment-ordered weights, built by prep_kernel.
// B-frag layout for 16x16x32: lane holds B[k=8*(lane>>4)+j][n=16*t+(lane&15)]
__device__ h8 g_W1f[4*64];      // [t][lane], k 9..31 zero-padded
__device__ h8 g_W2f[2*4*64];    // [c][t][lane], k = 32c+...
__device__ h8 g_Wg1f[4*4*64];   // [c][t][lane], k = 32c+..., 128 total
__device__ h8 g_Wg2f[2*64];     // [c][lane], n>=2 zero-padded
__device__ float g_cc[2];       // C0 = sum ln_b*Wo, C1 = sum ln_g*Wo

__global__ void prep_kernel(const float* __restrict__ W1, const float* __restrict__ W2,
                            const float* __restrict__ Wg1, const float* __restrict__ Wg2,
                            const float* __restrict__ ln_g, const float* __restrict__ ln_b,
                            const float* __restrict__ Wo)
{
    int idx = blockIdx.x * 256 + threadIdx.x;
    if (idx < 256) {
        int t = idx >> 6, lane = idx & 63, q = lane >> 4, nn = lane & 15;
        h8 v;
#pragma unroll
        for (int j = 0; j < 8; ++j) { int k = 8*q + j; v[j] = (_Float16)((k < 9) ? W1[k*64 + 16*t + nn] : 0.f); }
        g_W1f[idx] = v;
    } else if (idx < 768) {
        int z = idx - 256; int c = z >> 8, t = (z >> 6) & 3, lane = z & 63, q = lane >> 4, nn = lane & 15;
        h8 v;
#pragma unroll
        for (int j = 0; j < 8; ++j) { int k = 32*c + 8*q + j; v[j] = (_Float16)W2[k*64 + 16*t + nn]; }
        g_W2f[z] = v;
    } else if (idx < 1792) {
        int z = idx - 768; int c = z >> 8, t = (z >> 6) & 3, lane = z & 63, q = lane >> 4, nn = lane & 15;
        h8 v;
#pragma unroll
        for (int j = 0; j < 8; ++j) { int k = 32*c + 8*q + j; v[j] = (_Float16)Wg1[k*64 + 16*t + nn]; }
        g_Wg1f[z] = v;
    } else if (idx < 1920) {
        int z = idx - 1792; int c = z >> 6, lane = z & 63, q = lane >> 4, nn = lane & 15;
        h8 v;
#pragma unroll
        for (int j = 0; j < 8; ++j) { int k = 32*c + 8*q + j; v[j] = (_Float16)((nn < 2) ? Wg2[k*2 + nn] : 0.f); }
        g_Wg2f[z] = v;
    } else if (idx == 1920) {
        float c0 = 0.f, c1 = 0.f;
        for (int k = 0; k < 64; ++k) { c0 += ln_b[k]*Wo[k]; c1 += ln_g[k]*Wo[k]; }
        g_cc[0] = c0; g_cc[1] = c1;
    }
}

__device__ __forceinline__ float sig(float x) { return __builtin_amdgcn_rcpf(1.f + __expf(-x)); }

__device__ __forceinline__ f4 silu4(f4 v)
{
    f4 r; r[0] = v[0]*sig(v[0]); r[1] = v[1]*sig(v[1]); r[2] = v[2]*sig(v[2]); r[3] = v[3]*sig(v[3]);
    return r;
}

__device__ __forceinline__ f4 reduce16(f4 v)  // sum over the 16 lanes of each quad-group
{
#pragma unroll
    for (int m = 1; m < 16; m <<= 1) {
        v[0] += __shfl_xor(v[0], m); v[1] += __shfl_xor(v[1], m);
        v[2] += __shfl_xor(v[2], m); v[3] += __shfl_xor(v[3], m);
    }
    return v;
}

__device__ __forceinline__ void st72(_Float16* p, f4 v)   // C-frag -> LDS row stride 72
{ p[0] = (_Float16)v[0]; p[72] = (_Float16)v[1]; p[144] = (_Float16)v[2]; p[216] = (_Float16)v[3]; }

__device__ __forceinline__ void st136(_Float16* p, f4 v)  // row stride 136
{ p[0] = (_Float16)v[0]; p[136] = (_Float16)v[1]; p[272] = (_Float16)v[2]; p[408] = (_Float16)v[3]; }

// LDS budget: 16384 (Wg1 frags) + 4 waves * 11648 = 62976 B (<64K -> 2 blocks/CU)
// per-wave: feat 2*16*40h (rows padded to 40h vs 32: bank spread), h 2*16*72h,
// e 16*136h, logits 16*2 f32. g-tile aliases the h-tile (h dead by then).
__global__ __launch_bounds__(256, 2) void fused_kernel(
    const float* __restrict__ coords, const float* __restrict__ cost,
    const float* __restrict__ lscale, const float* __restrict__ b1,
    const float* __restrict__ b2, const float* __restrict__ fgam,
    const float* __restrict__ fbet, const float* __restrict__ bg1,
    const float* __restrict__ bg2, const float* __restrict__ gt,
    const float* __restrict__ lng, const float* __restrict__ Wo,
    const float* __restrict__ bo, float* __restrict__ out)
{
    __shared__ __align__(16) char smem[16384 + 4*11648];
    const int tid = threadIdx.x;
    const int wave = tid >> 6, lane = tid & 63;
    const int q = lane >> 4, nn = lane & 15;

    h8* wgv = (h8*)smem;                      // 1024 h8 = 16 KB, [c][t][lane]
    wgv[tid] = g_Wg1f[tid]; wgv[tid+256] = g_Wg1f[tid+256];
    wgv[tid+512] = g_Wg1f[tid+512]; wgv[tid+768] = g_Wg1f[tid+768];
    __syncthreads();

    char* wbase = smem + 16384 + wave*11648;
    _Float16* featL = (_Float16*)wbase;       // 1280 halfs
    _Float16* hL    = featL + 1280;           // 2304 halfs (also gL)
    _Float16* eL    = hL + 2304;              // 2176 halfs
    float*    logL  = (float*)(eL + 2176);    // 32 f32
    _Float16* gL    = hL;

    for (int z = lane; z < 1280; z += 64) featL[z] = (_Float16)0.f;  // pads stay zero

    // register-resident B-frags
    h8 w1f0 = g_W1f[lane],     w1f1 = g_W1f[64+lane],  w1f2 = g_W1f[128+lane], w1f3 = g_W1f[192+lane];
    h8 w2f00 = g_W2f[lane],     w2f01 = g_W2f[64+lane],  w2f02 = g_W2f[128+lane], w2f03 = g_W2f[192+lane];
    h8 w2f10 = g_W2f[256+lane], w2f11 = g_W2f[320+lane], w2f12 = g_W2f[384+lane], w2f13 = g_W2f[448+lane];
    h8 wg2f0 = g_Wg2f[lane],    wg2f1 = g_Wg2f[64+lane];

    const float b1c0 = b1[nn], b1c1 = b1[16+nn], b1c2 = b1[32+nn], b1c3 = b1[48+nn];
    const float b2c0 = b2[nn], b2c1 = b2[16+nn], b2c2 = b2[32+nn], b2c3 = b2[48+nn];
    const float bgc0 = bg1[nn], bgc1 = bg1[16+nn], bgc2 = bg1[32+nn], bgc3 = bg1[48+nn];
    const float fg00 = fgam[nn], fg01 = fgam[16+nn], fg02 = fgam[32+nn], fg03 = fgam[48+nn];
    const float fg10 = fgam[64+nn], fg11 = fgam[80+nn], fg12 = fgam[96+nn], fg13 = fgam[112+nn];
    const float fb00 = fbet[nn], fb01 = fbet[16+nn], fb02 = fbet[32+nn], fb03 = fbet[48+nn];
    const float fb10 = fbet[64+nn], fb11 = fbet[80+nn], fb12 = fbet[96+nn], fb13 = fbet[112+nn];
    const float gw0 = lng[nn]*Wo[nn], gw1 = lng[16+nn]*Wo[16+nn];
    const float gw2 = lng[32+nn]*Wo[32+nn], gw3 = lng[48+nn]*Wo[48+nn];
    const float s0 = __expf(lscale[0]), s1 = __expf(lscale[1]);
    const float invT = __expf(-gt[0]);
    const float outc = g_cc[0] + bo[0], C1 = g_cc[1];
    const float lgb = (nn < 2) ? bg2[nn] : 0.f;

    const int wgid = blockIdx.x*4 + wave;

    for (int it = 0; it < ITERS; ++it) {
        const int T = wgid + it*(BLOCKS*4);
        const int p0 = T*16;
        // ---- features: lanes 0-15 -> cost channel, 16-31 -> angle channel ----
        const int bb = p0 >> 16, ii = (p0 >> 8) & 255, j0 = p0 & 255;
        const float xc = cost[p0 + nn];
        const float* cb = coords + (bb << 9);
        const float xi = cb[2*ii], yi = cb[2*ii+1];
        const float xj = cb[2*(j0+nn)], yj = cb[2*(j0+nn)+1];
        const float ang = atan2f(yi - yj, xi - xj);
        const int isA = q & 1;
        const float xv = isA ? ang : xc;
        const float sE = isA ? s1 : s0;
        const float F0 = xv*sE;
        const float sn1 = __sinf(xv)*sE,      cs1 = __cosf(xv)*sE;
        const float sn2 = __sinf(2.f*xv)*sE,  cs2 = __cosf(2.f*xv)*sE;
        const float sn4 = __sinf(4.f*xv)*sE,  cs4 = __cosf(4.f*xv)*sE;
        const float sn8 = __sinf(8.f*xv)*sE,  cs8 = __cosf(8.f*xv)*sE;
        if (lane < 32) {
            _Float16* fp = featL + isA*640 + nn*40;
            h2 t0; t0[0]=(_Float16)F0;  t0[1]=(_Float16)sn1; *(h2*)(fp+0)=t0;
            h2 t1; t1[0]=(_Float16)cs1; t1[1]=(_Float16)sn2; *(h2*)(fp+2)=t1;
            h2 t2; t2[0]=(_Float16)cs2; t2[1]=(_Float16)sn4; *(h2*)(fp+4)=t2;
            h2 t3; t3[0]=(_Float16)cs4; t3[1]=(_Float16)sn8; *(h2*)(fp+6)=t3;
            h2 t4; t4[0]=(_Float16)cs8; t4[1]=(_Float16)0.f; *(h2*)(fp+8)=t4;
        }
        // ---- L1: feats(16 pad 32) @ W1 -> silu -> hLDS ----
        h8 aF0 = *(h8*)(featL + nn*40 + q*8);
        h8 aF1 = *(h8*)(featL + 640 + nn*40 + q*8);
        _Float16* hw0 = hL + q*288 + nn;
        _Float16* hw1 = hL + 1152 + q*288 + nn;
        { f4 a = {b1c0,b1c0,b1c0,b1c0}; a = MFMA(aF0, w1f0, a); st72(hw0,      silu4(a)); }
        { f4 a = {b1c1,b1c1,b1c1,b1c1}; a = MFMA(aF0, w1f1, a); st72(hw0+16,   silu4(a)); }
        { f4 a = {b1c2,b1c2,b1c2,b1c2}; a = MFMA(aF0, w1f2, a); st72(hw0+32,   silu4(a)); }
        { f4 a = {b1c3,b1c3,b1c3,b1c3}; a = MFMA(aF0, w1f3, a); st72(hw0+48,   silu4(a)); }
        { f4 a = {b1c0,b1c0,b1c0,b1c0}; a = MFMA(aF1, w1f0, a); st72(hw1,      silu4(a)); }
        { f4 a = {b1c1,b1c1,b1c1,b1c1}; a = MFMA(aF1, w1f1, a); st72(hw1+16,   silu4(a)); }
        { f4 a = {b1c2,b1c2,b1c2,b1c2}; a = MFMA(aF1, w1f2, a); st72(hw1+32,   silu4(a)); }
        { f4 a = {b1c3,b1c3,b1c3,b1c3}; a = MFMA(aF1, w1f3, a); st72(hw1+48,   silu4(a)); }
        // ---- L2: h @ W2 + b2, FiLM; keep e in f32 regs, also f16 -> eLDS ----
        h8 a00 = *(h8*)(hL + nn*72 + q*8);
        h8 a01 = *(h8*)(hL + nn*72 + 32 + q*8);
        h8 a10 = *(h8*)(hL + 1152 + nn*72 + q*8);
        h8 a11 = *(h8*)(hL + 1152 + nn*72 + 32 + q*8);
        _Float16* ew = eL + q*544 + nn;
        f4 e00,e01,e02,e03,e10,e11,e12,e13;
        { f4 a={b2c0,b2c0,b2c0,b2c0}; a=MFMA(a00,w2f00,a); a=MFMA(a01,w2f10,a); e00=a*fg00+fb00; st136(ew,     e00); }
        { f4 a={b2c1,b2c1,b2c1,b2c1}; a=MFMA(a00,w2f01,a); a=MFMA(a01,w2f11,a); e01=a*fg01+fb01; st136(ew+16,  e01); }
        { f4 a={b2c2,b2c2,b2c2,b2c2}; a=MFMA(a00,w2f02,a); a=MFMA(a01,w2f12,a); e02=a*fg02+fb02; st136(ew+32,  e02); }
        { f4 a={b2c3,b2c3,b2c3,b2c3}; a=MFMA(a00,w2f03,a); a=MFMA(a01,w2f13,a); e03=a*fg03+fb03; st136(ew+48,  e03); }
        { f4 a={b2c0,b2c0,b2c0,b2c0}; a=MFMA(a10,w2f00,a); a=MFMA(a11,w2f10,a); e10=a*fg10+fb10; st136(ew+64,  e10); }
        { f4 a={b2c1,b2c1,b2c1,b2c1}; a=MFMA(a10,w2f01,a); a=MFMA(a11,w2f11,a); e11=a*fg11+fb11; st136(ew+80,  e11); }
        { f4 a={b2c2,b2c2,b2c2,b2c2}; a=MFMA(a10,w2f02,a); a=MFMA(a11,w2f12,a); e12=a*fg12+fb12; st136(ew+96,  e12); }
        { f4 a={b2c3,b2c3,b2c3,b2c3}; a=MFMA(a10,w2f03,a); a=MFMA(a11,w2f13,a); e13=a*fg13+fb13; st136(ew+112, e13); }
        // ---- gate1: [e0|e1] @ Wg1 + bg1 -> silu -> gLDS (aliases hL) ----
        h8 ae0 = *(h8*)(eL + nn*136 + q*8);
        h8 ae1 = *(h8*)(eL + nn*136 + 32 + q*8);
        h8 ae2 = *(h8*)(eL + nn*136 + 64 + q*8);
        h8 ae3 = *(h8*)(eL + nn*136 + 96 + q*8);
        _Float16* gw_ = gL + q*288 + nn;
        { f4 a={bgc0,bgc0,bgc0,bgc0}; a=MFMA(ae0,wgv[lane],a); a=MFMA(ae1,wgv[256+lane],a); a=MFMA(ae2,wgv[512+lane],a); a=MFMA(ae3,wgv[768+lane],a); st72(gw_,    silu4(a)); }
        { f4 a={bgc1,bgc1,bgc1,bgc1}; a=MFMA(ae0,wgv[64+lane],a); a=MFMA(ae1,wgv[320+lane],a); a=MFMA(ae2,wgv[576+lane],a); a=MFMA(ae3,wgv[832+lane],a); st72(gw_+16, silu4(a)); }
        { f4 a={bgc2,bgc2,bgc2,bgc2}; a=MFMA(ae0,wgv[128+lane],a); a=MFMA(ae1,wgv[384+lane],a); a=MFMA(ae2,wgv[640+lane],a); a=MFMA(ae3,wgv[896+lane],a); st72(gw_+32, silu4(a)); }
        { f4 a={bgc3,bgc3,bgc3,bgc3}; a=MFMA(ae0,wgv[192+lane],a); a=MFMA(ae1,wgv[448+lane],a); a=MFMA(ae2,wgv[704+lane],a); a=MFMA(ae3,wgv[960+lane],a); st72(gw_+48, silu4(a)); }
        // ---- gate2: g @ Wg2 (N pad 16) ----
        h8 ag0 = *(h8*)(gL + nn*72 + q*8);
        h8 ag1 = *(h8*)(gL + nn*72 + 32 + q*8);
        f4 lg = {lgb, lgb, lgb, lgb};
        lg = MFMA(ag0, wg2f0, lg); lg = MFMA(ag1, wg2f1, lg);
        if (nn < 2) {
            logL[(q*4+0)*2+nn] = lg[0]; logL[(q*4+1)*2+nn] = lg[1];
            logL[(q*4+2)*2+nn] = lg[2]; logL[(q*4+3)*2+nn] = lg[3];
        }
        f2 lw0 = *(f2*)(logL + (q*4+0)*2);
        f2 lw1 = *(f2*)(logL + (q*4+1)*2);
        f2 lw2 = *(f2*)(logL + (q*4+2)*2);
        f2 lw3 = *(f2*)(logL + (q*4+3)*2);
        f4 w1v;
        w1v[0] = sig((lw0[1]-lw0[0])*invT); w1v[1] = sig((lw1[1]-lw1[0])*invT);
        w1v[2] = sig((lw2[1]-lw2[0])*invT); w1v[3] = sig((lw3[1]-lw3[0])*invT);
        // ---- fuse + LayerNorm + head ----
        f4 fu0 = e00 + w1v*(e10-e00);
        f4 fu1 = e01 + w1v*(e11-e01);
        f4 fu2 = e02 + w1v*(e12-e02);
        f4 fu3 = e03 + w1v*(e13-e03);
        f4 sv = reduce16((fu0+fu1)+(fu2+fu3));
        f4 mu = sv * (1.f/64.f);
        f4 d0 = fu0-mu, d1 = fu1-mu, d2 = fu2-mu, d3 = fu3-mu;
        f4 vv = reduce16((d0*d0+d1*d1)+(d2*d2+d3*d3)) * (1.f/64.f);
        f4 rs;
        rs[0] = __builtin_amdgcn_rsqf(vv[0]+1e-5f); rs[1] = __builtin_amdgcn_rsqf(vv[1]+1e-5f);
        rs[2] = __builtin_amdgcn_rsqf(vv[2]+1e-5f); rs[3] = __builtin_amdgcn_rsqf(vv[3]+1e-5f);
        f4 dt = reduce16((fu0*gw0 + fu1*gw1) + (fu2*gw2 + fu3*gw3));
        f4 o = rs*(dt - mu*C1) + outc;
        if (nn == 0) *(f4*)(out + p0 + q*4) = o;
    }
}

extern "C" void kernel_launch(void* const* d_in, const int* in_sizes, int n_in,
                              void* d_out, int out_size, void* d_ws, size_t ws_size,
                              hipStream_t stream)
{
    const float* coords = (const float*)d_in[0];
    const float* cost   = (const float*)d_in[1];
    const float* lscale = (const float*)d_in[2];
    const float* W1     = (const float*)d_in[3];
    const float* b1     = (const float*)d_in[4];
    const float* W2     = (const float*)d_in[5];
    const float* b2     = (const float*)d_in[6];
    const float* fg     = (const float*)d_in[7];
    const float* fb     = (const float*)d_in[8];
    const float* Wg1    = (const float*)d_in[9];
    const float* bg1    = (const float*)d_in[10];
    const float* Wg2    = (const float*)d_in[11];
    const float* bg2    = (const float*)d_in[12];
    const float* gt     = (const float*)d_in[13];
    const float* lng    = (const float*)d_in[14];
    const float* lnb    = (const float*)d_in[15];
    const float* Wo     = (const float*)d_in[16];
    const float* bo     = (const float*)d_in[17];
    float* out = (float*)d_out;

    prep_kernel<<<8, 256, 0, stream>>>(W1, W2, Wg1, Wg2, lng, lnb, Wo);
    fused_kernel<<<BLOCKS, 256, 0, stream>>>(
        coords, cost, lscale, b1, b2, fg, fb, bg1, bg2, gt, lng, Wo, bo, out);
}